// Round 1
// baseline (131.882 us; speedup 1.0000x reference)
//
#include <hip/hip_runtime.h>
#include <math.h>

// One block (256 threads) per video row b. T = 4096 = 256 chunks x 16.
// LDS: masked p1/p2 arrays stored chunk-padded (stride 17 floats) so that
// chunk-sequential accesses (16*c + i) hit all 32 banks (17 coprime to 32)
// instead of the 2-bank / 32-way-conflict pathology of 16-aligned bases.

#define T_LEN 4096
#define NCH   256      // number of chunks == threads per block
#define CH    16       // chunk length == DELTA
#define PADS  17       // padded chunk stride in floats
#define NEGV  (-1e30f)
#define NEGH  (-5e29f) // NEG/2 threshold, matches reference "> NEG/2"

__device__ __forceinline__ int pidx(int t) { return (t >> 4) * PADS + (t & 15); }

__device__ __forceinline__ void amax_comb(float& v, int& i, float ov, int oi) {
  // argmax with first-index (smallest idx) tie-break — matches jnp.argmax
  if (ov > v || (ov == v && oi < i)) { v = ov; i = oi; }
}

__global__ __launch_bounds__(256, 4) void lftc_kernel(
    const float* __restrict__ s1s2,  // [B, T, 2]
    const float* __restrict__ act,   // [B, T]
    const int*   __restrict__ lens,  // [B]
    const float* __restrict__ vls,   // [B]
    float* __restrict__ out)         // [2]: state_sum, 0.2*action_sum
{
  __shared__ float P1s[NCH * PADS];
  __shared__ float P2s[NCH * PADS];
  __shared__ float cm1[NCH];
  __shared__ float cm2[NCH];
  __shared__ float redv[4];
  __shared__ int   redi[4];
  __shared__ int   s_ac, s_s1, s_s2;

  const int b    = blockIdx.x;
  const int tid  = threadIdx.x;
  const int lane = tid & 63;
  const int wv   = tid >> 6;
  const int len  = lens[b];
  const float w  = vls[b];

  const float* __restrict__ srow = s1s2 + (size_t)b * T_LEN * 2;
  const float* __restrict__ zrow = act  + (size_t)b * T_LEN;

  // ---------- phase 1: load, softmax, mask; accumulate ac-independent BCE ----------
  // action_sum = sum_valid softplus(z) + window correction (added later).
  float sp_partial = 0.f;
#pragma unroll
  for (int k = 0; k < CH; k++) {
    int t = k * NCH + tid;                       // coalesced
    float2 ll = *(const float2*)(srow + 2 * t);
    float m  = fmaxf(ll.x, ll.y);
    float e1 = expf(ll.x - m), e2 = expf(ll.y - m);
    float inv = 1.f / (e1 + e2);
    bool v = t < len;
    P1s[pidx(t)] = v ? e1 * inv : NEGV;
    P2s[pidx(t)] = v ? e2 * inv : NEGV;
    float z = zrow[t];
    if (v) sp_partial += fmaxf(z, 0.f) + log1pf(expf(-fabsf(z)));  // softplus(z)
  }
  __syncthreads();

  // ---------- phase 2: per-chunk maxima ----------
  {
    int base = tid * PADS;
    float m1 = NEGV, m2 = NEGV;
#pragma unroll
    for (int i = 0; i < CH; i++) {
      m1 = fmaxf(m1, P1s[base + i]);
      m2 = fmaxf(m2, P2s[base + i]);
    }
    cm1[tid] = m1;
    cm2[tid] = m2;
  }
  __syncthreads();

  // ---------- phase 3: inclusive prefix-max scan (cm1) + suffix-max scan (cm2) ----------
  {
    float v1 = cm1[tid];
    float v2 = cm2[tid];
    for (int off = 1; off < NCH; off <<= 1) {
      float o1 = (tid >= off)       ? cm1[tid - off] : NEGV;
      float o2 = (tid + off < NCH)  ? cm2[tid + off] : NEGV;
      __syncthreads();
      v1 = fmaxf(v1, o1);
      v2 = fmaxf(v2, o2);
      cm1[tid] = v1;
      cm2[tid] = v2;
      __syncthreads();
    }
    // cm1[c] = max p1m over chunks [0..c]; cm2[c] = max p2m over chunks [c..255]
  }

  // ---------- phase 4: score[t] = pre[t-16] * pa[t] * suf[t+16], block argmax -> ac ----------
  float best = NEGV;
  int   bidx = tid * CH;  // all-NEG rows reduce to global idx 0, matching jnp.argmax
  {
    const int j = tid;
    // reverse cummax of chunk j+1 (provides suf[t+16] for t in chunk j)
    float rs[CH];
    if (j <= NCH - 2) {
      float run = (j + 2 <= NCH - 1) ? cm2[j + 2] : NEGV;
      int b2 = (j + 1) * PADS;
#pragma unroll
      for (int i = CH - 1; i >= 0; --i) { run = fmaxf(run, P2s[b2 + i]); rs[i] = run; }
    }
    // z for this chunk: 4x float4, wave covers 4KB contiguous
    float zz[CH];
    {
      const float4* zp = reinterpret_cast<const float4*>(zrow + j * CH);
      float4 q0 = zp[0], q1 = zp[1], q2 = zp[2], q3 = zp[3];
      zz[0] = q0.x; zz[1] = q0.y; zz[2]  = q0.z; zz[3]  = q0.w;
      zz[4] = q1.x; zz[5] = q1.y; zz[6]  = q1.z; zz[7]  = q1.w;
      zz[8] = q2.x; zz[9] = q2.y; zz[10] = q2.z; zz[11] = q2.w;
      zz[12] = q3.x; zz[13] = q3.y; zz[14] = q3.z; zz[15] = q3.w;
    }
    float prerun = (j >= 2) ? cm1[j - 2] : NEGV;  // max over chunks [0..j-2]
    int b1 = (j - 1) * PADS;
#pragma unroll
    for (int i = 0; i < CH; i++) {
      int t = j * CH + i;
      float pre_s;
      if (j >= 1) { prerun = fmaxf(prerun, P1s[b1 + i]); pre_s = prerun; }
      else        { pre_s = NEGV; }
      float suf_s = (j <= NCH - 2) ? rs[i] : NEGV;
      if (pre_s > NEGH && suf_s > NEGH && t < len) {
        float pa = 1.f / (1.f + expf(-zz[i]));
        float sc = (pre_s * pa) * suf_s;
        if (sc > best) { best = sc; bidx = t; }  // strict > keeps first occurrence
      }
    }
  }
#pragma unroll
  for (int off = 32; off; off >>= 1) {
    float ov = __shfl_down(best, off);
    int   oi = __shfl_down(bidx, off);
    amax_comb(best, bidx, ov, oi);
  }
  if (lane == 0) { redv[wv] = best; redi[wv] = bidx; }
  __syncthreads();
  if (tid == 0) {
    float v = redv[0]; int i = redi[0];
    for (int q = 1; q < 4; q++) amax_comb(v, i, redv[q], redi[q]);
    s_ac = i;
  }
  __syncthreads();
  const int ac = s_ac;

  // ---------- phase 5: s1 = argmax p1m over [0, ac-16]; s2 = argmax p2m over [ac+16, T) ----------
  {
    float v1 = NEGV; int i1 = 0;
    const int e1lim = ac - CH;
#pragma unroll
    for (int k = 0; k < CH; k++) {
      int t = k * NCH + tid;
      if (t <= e1lim) { float p = P1s[pidx(t)]; if (p > v1) { v1 = p; i1 = t; } }
    }
#pragma unroll
    for (int off = 32; off; off >>= 1) {
      float ov = __shfl_down(v1, off);
      int   oi = __shfl_down(i1, off);
      amax_comb(v1, i1, ov, oi);
    }
    if (lane == 0) { redv[wv] = v1; redi[wv] = i1; }
    __syncthreads();
    if (tid == 0) {
      float v = redv[0]; int i = redi[0];
      for (int q = 1; q < 4; q++) amax_comb(v, i, redv[q], redi[q]);
      s_s1 = i;
    }
    __syncthreads();

    float v2 = NEGV; int i2 = 0;
    const int s2lo = ac + CH;
#pragma unroll
    for (int k = 0; k < CH; k++) {
      int t = k * NCH + tid;
      if (t >= s2lo) { float p = P2s[pidx(t)]; if (p > v2) { v2 = p; i2 = t; } }
    }
#pragma unroll
    for (int off = 32; off; off >>= 1) {
      float ov = __shfl_down(v2, off);
      int   oi = __shfl_down(i2, off);
      amax_comb(v2, i2, ov, oi);
    }
    if (lane == 0) { redv[wv] = v2; redi[wv] = i2; }
    __syncthreads();
    if (tid == 0) {
      float v = redv[0]; int i = redi[0];
      for (int q = 1; q < 4; q++) amax_comb(v, i, redv[q], redi[q]);
      s_s2 = i;
    }
    __syncthreads();
  }

  // ---------- phase 6: action window correction + block sum + losses ----------
  // bce(y=1) = softplus(-z) = max(z,0) - z + log1p(exp(-|z|)); w=10 inside window (valid),
  // replacing the base softplus(z) (w=1) term.
  if (tid < 9) {
    int t = ac - 4 + tid;
    if (t >= 0 && t < T_LEN && t < len) {
      float z  = zrow[t];
      float sp = log1pf(expf(-fabsf(z)));
      float b0 = fmaxf(z, 0.f) + sp;   // softplus(z)
      float b1 = b0 - z;               // softplus(-z)
      sp_partial += 10.f * b1 - b0;
    }
  }
  float s = sp_partial;
#pragma unroll
  for (int off = 32; off; off >>= 1) s += __shfl_down(s, off);
  if (lane == 0) redv[wv] = s;
  __syncthreads();
  if (tid == 0) {
    float tot = redv[0] + redv[1] + redv[2] + redv[3];
    atomicAdd(out + 1, 0.2f * w * tot);

    const int s1 = s_s1, s2 = s_s2;
    const float* q1 = srow + 2 * (size_t)s1;
    const float* q2 = srow + 2 * (size_t)s2;
    float a0 = q1[0], a1 = q1[1];
    float m1 = fmaxf(a0, a1);
    float lse1 = m1 + logf(expf(a0 - m1) + expf(a1 - m1));
    float loss1 = -(a0 - lse1);          // -log_softmax[...,0] at s1
    float c0 = q2[0], c1 = q2[1];
    float m2 = fmaxf(c0, c1);
    float lse2 = m2 + logf(expf(c0 - m2) + expf(c1 - m2));
    float loss2 = -(c1 - lse2);          // -log_softmax[...,1] at s2
    atomicAdd(out + 0, w * (loss1 + loss2));
  }
}

extern "C" void kernel_launch(void* const* d_in, const int* in_sizes, int n_in,
                              void* d_out, int out_size, void* d_ws, size_t ws_size,
                              hipStream_t stream) {
  const float* s1s2 = (const float*)d_in[0];
  const float* act  = (const float*)d_in[1];
  const int*   lens = (const int*)d_in[2];
  const float* vls  = (const float*)d_in[3];
  float* out = (float*)d_out;

  const int B = in_sizes[2];  // lens has B elements; T fixed at 4096 per problem shape

  hipMemsetAsync(out, 0, (size_t)out_size * sizeof(float), stream);
  lftc_kernel<<<B, 256, 0, stream>>>(s1s2, act, lens, vls, out);
}

// Round 2
// 98.314 us; speedup vs baseline: 1.3414x; 1.3414x over previous
//
#include <hip/hip_runtime.h>
#include <math.h>

// One block (256 threads) per video row. T = 4096 = 256 chunks x 16 (CH == DELTA).
// Thread j owns chunk j: loads it as float4s, keeps z[16] in registers, computes
// chunk maxima in registers, stores masked p1 to LDS (p2 = 1-p1 recomputed on read).
// Prefix/suffix cummax over 256 chunk maxima via wave shuffles + 4-wave combine.
// Per-block partial losses go to d_ws; a second tiny kernel reduces to d_out.

#define T_LEN 4096
#define NCH   256
#define CH    16
#define PADS  17       // padded chunk stride: bank (17j+i)%32 -> 2-way max (free)
#define NEGV  (-1e30f)
#define NEGH  (-5e29f)

__device__ __forceinline__ float frcp(float x) { return __builtin_amdgcn_rcpf(x); }

__device__ __forceinline__ void amax_comb(float& v, int& i, float ov, int oi) {
  // argmax, first-occurrence (smallest index) tie-break — matches jnp.argmax
  if (ov > v || (ov == v && oi < i)) { v = ov; i = oi; }
}

__global__ __launch_bounds__(256, 4) void lftc_main(
    const float* __restrict__ s1s2,  // [B, T, 2]
    const float* __restrict__ act,   // [B, T]
    const int*   __restrict__ lens,  // [B]
    const float* __restrict__ vls,   // [B]
    float* __restrict__ ws)          // [B, 2]: {state_partial, action_partial}
{
  __shared__ float P1s[NCH * PADS];          // masked p1 (p2 = 1-p1 where valid)
  __shared__ float cm1[NCH];                 // inclusive prefix-max of chunk p1-maxima
  __shared__ float cm2[NCH];                 // inclusive suffix-max of chunk p2-maxima
  __shared__ float wag1[4], wag2[4];
  __shared__ float redv[4];  __shared__ int redi[4];
  __shared__ float redv2[4]; __shared__ int redi2[4];
  __shared__ float redv3[4]; __shared__ int redi3[4];
  __shared__ int   s_ac;

  const int b    = blockIdx.x;
  const int tid  = threadIdx.x;
  const int lane = tid & 63;
  const int wv   = tid >> 6;
  const int len  = lens[b];
  const float w  = vls[b];

  const float* __restrict__ srow = s1s2 + (size_t)b * T_LEN * 2;
  const float* __restrict__ zrow = act  + (size_t)b * T_LEN;

  const int j    = tid;
  const int base = j * CH;

  // ---------- phase 1: batch-load chunk, softmax via single exp, chunk maxima ----------
  float4 sv[8];
  {
    const float4* sp4 = reinterpret_cast<const float4*>(srow + 2 * base);
#pragma unroll
    for (int k = 0; k < 8; k++) sv[k] = sp4[k];
  }
  float4 zv[4];
  {
    const float4* zp4 = reinterpret_cast<const float4*>(zrow + base);
#pragma unroll
    for (int k = 0; k < 4; k++) zv[k] = zp4[k];
  }
  const float* sf = reinterpret_cast<const float*>(sv);
  float z[16];
  {
    const float* zf = reinterpret_cast<const float*>(zv);
#pragma unroll
    for (int i = 0; i < 16; i++) z[i] = zf[i];
  }

  float m1 = NEGV, m2 = NEGV, sp_part = 0.f;
#pragma unroll
  for (int i = 0; i < CH; i++) {
    float lx = sf[2 * i], ly = sf[2 * i + 1];
    float p  = frcp(1.f + __expf(ly - lx));       // p1 = softmax[...,0]
    bool  v  = (base + i) < len;
    float p1m = v ? p : NEGV;
    float p2m = v ? 1.f - p : NEGV;
    P1s[j * PADS + i] = p1m;
    m1 = fmaxf(m1, p1m);
    m2 = fmaxf(m2, p2m);
    float zi = z[i];
    if (v) sp_part += fmaxf(zi, 0.f) + __logf(1.f + __expf(-fabsf(zi)));  // softplus(z)
  }

  // ---------- phase 2: prefix-max scan (m1) + suffix-max scan (m2) over 256 chunks ----------
  {
    float pm = m1;
#pragma unroll
    for (int off = 1; off < 64; off <<= 1) {
      float o = __shfl_up(pm, off);
      if (lane >= off) pm = fmaxf(pm, o);
    }
    float sm = m2;
#pragma unroll
    for (int off = 1; off < 64; off <<= 1) {
      float o = __shfl_down(sm, off);
      if (lane + off < 64) sm = fmaxf(sm, o);
    }
    if (lane == 63) wag1[wv] = pm;   // wave total (prefix side)
    if (lane == 0)  wag2[wv] = sm;   // wave total (suffix side)
    __syncthreads();
    float addp = NEGV, adds = NEGV;
#pragma unroll
    for (int q = 0; q < 4; q++) {
      if (q < wv) addp = fmaxf(addp, wag1[q]);
      if (q > wv) adds = fmaxf(adds, wag2[q]);
    }
    cm1[tid] = fmaxf(pm, addp);
    cm2[tid] = fmaxf(sm, adds);
    __syncthreads();   // also publishes P1s
  }

  // ---------- phase 3: score[t] = pre[t-16] * sigmoid(z[t]) * suf[t+16]; argmax -> ac ----------
  float best = NEGV;
  int   bidx = base;    // all-masked rows reduce to index 0 (matches jnp.argmax)
  {
    float rs[CH];       // suf_s for this chunk (reverse scan over neighbor chunk j+1)
    if (j <= NCH - 2) {
      float run = (j + 2 <= NCH - 1) ? cm2[j + 2] : NEGV;
      const int b2 = (j + 1) * PADS;
#pragma unroll
      for (int i = CH - 1; i >= 0; --i) {
        float p1n = P1s[b2 + i];
        float p2n = (p1n > NEGH) ? 1.f - p1n : NEGV;
        run = fmaxf(run, p2n);
        rs[i] = run;
      }
    }
    float prerun = (j >= 2) ? cm1[j - 2] : NEGV;
    const int b1 = (j - 1) * PADS;
#pragma unroll
    for (int i = 0; i < CH; i++) {
      float pre_s = NEGV;
      if (j >= 1) { prerun = fmaxf(prerun, P1s[b1 + i]); pre_s = prerun; }
      float suf_s = (j <= NCH - 2) ? rs[i] : NEGV;
      int t = base + i;
      if (pre_s > NEGH && suf_s > NEGH && t < len) {
        float pa = frcp(1.f + __expf(-z[i]));
        float sc = (pre_s * pa) * suf_s;
        if (sc > best) { best = sc; bidx = t; }   // strict > keeps first occurrence
      }
    }
  }
#pragma unroll
  for (int off = 32; off; off >>= 1) {
    float ov = __shfl_down(best, off);
    int   oi = __shfl_down(bidx, off);
    amax_comb(best, bidx, ov, oi);
  }
  if (lane == 0) { redv[wv] = best; redi[wv] = bidx; }
  __syncthreads();
  if (tid == 0) {
    float v = redv[0]; int i = redi[0];
    for (int q = 1; q < 4; q++) amax_comb(v, i, redv[q], redi[q]);
    s_ac = i;
  }
  __syncthreads();
  const int ac = s_ac;

  // ---------- phase 4: s1 = argmax p1m on [0, ac-16]; s2 = argmax p2m on [ac+16, T) ----------
  float v1 = NEGV; int i1 = 0;
  float v2 = NEGV; int i2 = 0;
  {
    const int e1   = ac - CH;
    const int s2lo = ac + CH;
#pragma unroll
    for (int k = 0; k < CH; k++) {
      int t = base + k;
      float p1v = P1s[j * PADS + k];
      if (t <= e1 && p1v > v1) { v1 = p1v; i1 = t; }
      float p2v = (p1v > NEGH) ? 1.f - p1v : NEGV;
      if (t >= s2lo && p2v > v2) { v2 = p2v; i2 = t; }
    }
#pragma unroll
    for (int off = 32; off; off >>= 1) {
      float ov1 = __shfl_down(v1, off); int oi1 = __shfl_down(i1, off);
      amax_comb(v1, i1, ov1, oi1);
      float ov2 = __shfl_down(v2, off); int oi2 = __shfl_down(i2, off);
      amax_comb(v2, i2, ov2, oi2);
    }
    if (lane == 0) { redv2[wv] = v1; redi2[wv] = i1; redv3[wv] = v2; redi3[wv] = i2; }
  }

  // ---------- phase 5: action window correction + block sum + output ----------
  if (tid < 9) {
    int t = ac - 4 + tid;
    if (t >= 0 && t < len) {
      float zc = zrow[t];
      float b0 = fmaxf(zc, 0.f) + __logf(1.f + __expf(-fabsf(zc)));  // softplus(z)
      sp_part += 10.f * (b0 - zc) - b0;   // 10*softplus(-z) replaces softplus(z)
    }
  }
  float s = sp_part;
#pragma unroll
  for (int off = 32; off; off >>= 1) s += __shfl_down(s, off);
  if (lane == 0) wag1[wv] = s;
  __syncthreads();
  if (tid == 0) {
    float tot = wag1[0] + wag1[1] + wag1[2] + wag1[3];

    float sv1 = redv2[0]; int s1 = redi2[0];
    float sv2 = redv3[0]; int s2 = redi3[0];
    for (int q = 1; q < 4; q++) {
      amax_comb(sv1, s1, redv2[q], redi2[q]);
      amax_comb(sv2, s2, redv3[q], redi3[q]);
    }
    // state CE: -log_softmax[s1,0] = softplus(l1-l0); -log_softmax[s2,1] = softplus(l0-l1)
    float a0 = srow[2 * (size_t)s1],     a1 = srow[2 * (size_t)s1 + 1];
    float c0 = srow[2 * (size_t)s2],     c1 = srow[2 * (size_t)s2 + 1];
    float d1 = a1 - a0;
    float loss1 = fmaxf(d1, 0.f) + __logf(1.f + __expf(-fabsf(d1)));
    float d2 = c0 - c1;
    float loss2 = fmaxf(d2, 0.f) + __logf(1.f + __expf(-fabsf(d2)));

    ws[2 * (size_t)b]     = w * (loss1 + loss2);
    ws[2 * (size_t)b + 1] = 0.2f * w * tot;
  }
}

__global__ void lftc_reduce(const float* __restrict__ ws, float* __restrict__ out, int B) {
  __shared__ float a0[4], a1[4];
  const int tid  = threadIdx.x;
  const int lane = tid & 63;
  const int wv   = tid >> 6;
  float s0 = 0.f, s1 = 0.f;
  for (int i = tid; i < B; i += 256) {
    s0 += ws[2 * (size_t)i];
    s1 += ws[2 * (size_t)i + 1];
  }
#pragma unroll
  for (int off = 32; off; off >>= 1) {
    s0 += __shfl_down(s0, off);
    s1 += __shfl_down(s1, off);
  }
  if (lane == 0) { a0[wv] = s0; a1[wv] = s1; }
  __syncthreads();
  if (tid == 0) {
    out[0] = a0[0] + a0[1] + a0[2] + a0[3];
    out[1] = a1[0] + a1[1] + a1[2] + a1[3];
  }
}

extern "C" void kernel_launch(void* const* d_in, const int* in_sizes, int n_in,
                              void* d_out, int out_size, void* d_ws, size_t ws_size,
                              hipStream_t stream) {
  const float* s1s2 = (const float*)d_in[0];
  const float* act  = (const float*)d_in[1];
  const int*   lens = (const int*)d_in[2];
  const float* vls  = (const float*)d_in[3];
  float* out = (float*)d_out;
  float* ws  = (float*)d_ws;

  const int B = in_sizes[2];   // lens has B elements; T fixed at 4096

  lftc_main<<<B, 256, 0, stream>>>(s1s2, act, lens, vls, ws);
  lftc_reduce<<<1, 256, 0, stream>>>(ws, out, B);
}